// Round 2
// baseline (767.100 us; speedup 1.0000x reference)
//
#include <hip/hip_runtime.h>
#include <hip/hip_bf16.h>
#include <cstdint>

#define L_SEQ 2048
#define HID   4096
#define NH    32
#define NKV   8
#define HD    128
#define MAXP  4096
#define KVD   (2*NKV*HD)   // 2048: fused K|V projection width

using bf16_t = __hip_bfloat16;
typedef __bf16 bf16x8 __attribute__((ext_vector_type(8)));
typedef float  f32x4  __attribute__((ext_vector_type(4)));
typedef short  short4v __attribute__((ext_vector_type(4)));
typedef short  short8v __attribute__((ext_vector_type(8)));

__device__ __forceinline__ void async_copy16(void* lds, const void* g) {
  __builtin_amdgcn_global_load_lds(
      (__attribute__((address_space(1))) void*)g,
      (__attribute__((address_space(3))) void*)lds, 16, 0, 0);
}

// ---------------- RMSNorm: x (L,HID) f32 -> h (L,HID) bf16 ----------------
__global__ __launch_bounds__(256) void rmsnorm_kernel(
    const float* __restrict__ x, const float* __restrict__ w,
    bf16_t* __restrict__ h) {
  int row = blockIdx.x, t = threadIdx.x;
  const float4* xv = (const float4*)(x + (size_t)row * HID);
  float4 v[4];
  float ss = 0.f;
#pragma unroll
  for (int i = 0; i < 4; i++) {
    v[i] = xv[i * 256 + t];
    ss += v[i].x * v[i].x + v[i].y * v[i].y + v[i].z * v[i].z + v[i].w * v[i].w;
  }
#pragma unroll
  for (int off = 32; off >= 1; off >>= 1) ss += __shfl_xor(ss, off, 64);
  __shared__ float red[4];
  if ((t & 63) == 0) red[t >> 6] = ss;
  __syncthreads();
  float rr = rsqrtf((red[0] + red[1] + red[2] + red[3]) * (1.0f / HID) + 1e-5f);
  const float4* wv = (const float4*)w;
  bf16_t* hr = h + (size_t)row * HID;
#pragma unroll
  for (int i = 0; i < 4; i++) {
    float4 wl = wv[i * 256 + t];
    bf16_t tmp[4];
    tmp[0] = __float2bfloat16(v[i].x * rr * wl.x);
    tmp[1] = __float2bfloat16(v[i].y * rr * wl.y);
    tmp[2] = __float2bfloat16(v[i].z * rr * wl.z);
    tmp[3] = __float2bfloat16(v[i].w * rr * wl.w);
    *(short4v*)(hr + (size_t)(i * 256 + t) * 4) = *(short4v*)tmp;
  }
}

// ---------------- f32 -> bf16 convert ----------------
__global__ __launch_bounds__(256) void cvt_bf16_kernel(
    const float* __restrict__ src, bf16_t* __restrict__ dst) {
  size_t i = ((size_t)blockIdx.x * 256 + threadIdx.x) * 8;
  float4 a = *(const float4*)(src + i);
  float4 b = *(const float4*)(src + i + 4);
  bf16_t tmp[8] = {__float2bfloat16(a.x), __float2bfloat16(a.y),
                   __float2bfloat16(a.z), __float2bfloat16(a.w),
                   __float2bfloat16(b.x), __float2bfloat16(b.y),
                   __float2bfloat16(b.z), __float2bfloat16(b.w)};
  *(short8v*)(dst + i) = *(short8v*)tmp;
}

// ---------------- GEMM: C(MxN) = A(MxK) @ B(NxK)^T, frag-ordered LDS -------
template <int OUT_MODE>
__global__ __launch_bounds__(256) void gemm_bt_kernel(
    const bf16_t* __restrict__ A, const bf16_t* __restrict__ B,
    bf16_t* __restrict__ Cb, float* __restrict__ Cf,
    const float* __restrict__ resid, int N, int K) {
  __shared__ alignas(16) bf16_t As[8 * 512];
  __shared__ alignas(16) bf16_t Bs[8 * 512];
  int t = threadIdx.x;
  int l = t & 63;
  int lane15 = l & 15, quad = l >> 4;
  int w = t >> 6;
  int wm = w >> 1, wn = w & 1;
  const bf16_t* Ag = A + (size_t)blockIdx.y * 128 * K;
  const bf16_t* Bg = B + (size_t)blockIdx.x * 128 * K;
  f32x4 acc[4][4] = {};
  for (int kt = 0; kt < K; kt += 32) {
    __syncthreads();
#pragma unroll
    for (int i = 0; i < 2; i++) {
      int p = w * 2 + i;
      async_copy16(&As[p * 512], Ag + (size_t)(p * 16 + lane15) * K + kt + quad * 8);
      async_copy16(&Bs[p * 512], Bg + (size_t)(p * 16 + lane15) * K + kt + quad * 8);
    }
    __syncthreads();
    bf16x8 af[4], bfr[4];
#pragma unroll
    for (int i = 0; i < 4; i++)
      af[i] = *(const bf16x8*)&As[(wm * 4 + i) * 512 + l * 8];
#pragma unroll
    for (int j = 0; j < 4; j++)
      bfr[j] = *(const bf16x8*)&Bs[(wn * 4 + j) * 512 + l * 8];
#pragma unroll
    for (int i = 0; i < 4; i++)
#pragma unroll
      for (int j = 0; j < 4; j++)
        acc[i][j] = __builtin_amdgcn_mfma_f32_16x16x32_bf16(af[i], bfr[j],
                                                            acc[i][j], 0, 0, 0);
  }
  int row0 = blockIdx.y * 128 + wm * 64 + quad * 4;
  int col0 = blockIdx.x * 128 + wn * 64 + lane15;
#pragma unroll
  for (int i = 0; i < 4; i++)
#pragma unroll
    for (int j = 0; j < 4; j++)
#pragma unroll
      for (int r = 0; r < 4; r++) {
        size_t idx = (size_t)(row0 + i * 16 + r) * N + col0 + j * 16;
        if (OUT_MODE == 0)
          Cb[idx] = __float2bfloat16(acc[i][j][r]);
        else
          Cf[idx] = acc[i][j][r] + resid[idx];
      }
}

// ---------------- RoPE in-place on q (L,HID) and k part of kv (L,KVD) -----
__global__ __launch_bounds__(256) void rope_kernel(
    bf16_t* __restrict__ q, bf16_t* __restrict__ kv,
    const float* __restrict__ cosT, const float* __restrict__ sinT,
    float* __restrict__ kc_out) {
  int idx = blockIdx.x * 256 + threadIdx.x;
  int d = idx & 63;
  int rest = idx >> 6;
  int hh = rest % (NH + NKV);
  int pos = rest / (NH + NKV);
  float c = cosT[pos * HD + d];
  float s = sinT[pos * HD + d];
  if (hh < NH) {
    bf16_t* b = q + (size_t)pos * HID + hh * HD;
    float x1 = __bfloat162float(b[d]);
    float x2 = __bfloat162float(b[d + 64]);
    b[d] = __float2bfloat16(x1 * c - x2 * s);
    b[d + 64] = __float2bfloat16(x2 * c + x1 * s);
  } else {
    int kh = hh - NH;
    bf16_t* b = kv + (size_t)pos * KVD + kh * HD;
    float x1 = __bfloat162float(b[d]);
    float x2 = __bfloat162float(b[d + 64]);
    float o1 = x1 * c - x2 * s;
    float o2 = x2 * c + x1 * s;
    b[d] = __float2bfloat16(o1);
    b[d + 64] = __float2bfloat16(o2);
    float* kc = kc_out + (size_t)pos * (NKV * HD) + kh * HD;
    kc[d] = o1;
    kc[d + 64] = o2;
  }
}

// ---------------- V transpose via LDS + v_cache fp32 write ----------------
__global__ __launch_bounds__(256) void vtrans_kernel(
    const bf16_t* __restrict__ kv, float* __restrict__ vc_out,
    bf16_t* __restrict__ vT) {
  __shared__ alignas(16) short Ts[64 * 64];
  int kvh = blockIdx.x, pb = blockIdx.y, db = blockIdx.z;
  int t = threadIdx.x;
  int r = t & 63;    // pos within tile
  int c4 = t >> 6;   // col-chunk of 16
  const short* src = (const short*)(kv + (size_t)(pb * 64 + r) * KVD +
                                    NKV * HD + kvh * HD + db * 64 + c4 * 16);
  short8v v0 = *(const short8v*)src;
  short8v v1 = *(const short8v*)(src + 8);
  float* vo = vc_out + (size_t)(pb * 64 + r) * (NKV * HD) + kvh * HD + db * 64 + c4 * 16;
  float tmpf[16];
#pragma unroll
  for (int j = 0; j < 8; j++) {
    tmpf[j]     = __uint_as_float(((unsigned)(unsigned short)v0[j]) << 16);
    tmpf[j + 8] = __uint_as_float(((unsigned)(unsigned short)v1[j]) << 16);
  }
#pragma unroll
  for (int j = 0; j < 4; j++)
    ((float4*)vo)[j] = make_float4(tmpf[j * 4], tmpf[j * 4 + 1],
                                   tmpf[j * 4 + 2], tmpf[j * 4 + 3]);
  int cs = c4 ^ (r & 3);
  *(short8v*)&Ts[r * 64 + cs * 16] = v0;
  *(short8v*)&Ts[r * 64 + cs * 16 + 8] = v1;
  __syncthreads();
  int dr = t & 63;   // d within tile
  int pc = t >> 6;   // pos chunk of 16
  short vals[16];
#pragma unroll
  for (int j = 0; j < 16; j++) {
    int pos = pc * 16 + j;
    int cc = (dr >> 4) ^ (pos & 3);
    vals[j] = Ts[pos * 64 + cc * 16 + (dr & 15)];
  }
  short* dst = (short*)(vT + ((size_t)kvh * HD + db * 64 + dr) * L_SEQ + pb * 64 + pc * 16);
  *(short8v*)dst = *(short8v*)&vals[0];
  *(short8v*)(dst + 8) = *(short8v*)&vals[8];
}

// ---------------- cache tail copy (pos >= L) ------------------------------
__global__ __launch_bounds__(256) void cache_tail_kernel(
    const float* __restrict__ kc_in, const float* __restrict__ vc_in,
    float* __restrict__ kc_out, float* __restrict__ vc_out) {
  size_t base = (size_t)L_SEQ * NKV * HD;
  size_t i = base + ((size_t)blockIdx.x * 256 + threadIdx.x) * 4;
  *(float4*)(kc_out + i) = *(const float4*)(kc_in + i);
  *(float4*)(vc_out + i) = *(const float4*)(vc_in + i);
}

// ---------------- Flash attention: block = (head, 128-row Q tile) ---------
__global__ __launch_bounds__(256) void attn_kernel(
    const bf16_t* __restrict__ qg, const bf16_t* __restrict__ kvg,
    const bf16_t* __restrict__ vT, bf16_t* __restrict__ attn) {
  int h = blockIdx.x;
  int qblk = blockIdx.y;
  int kvh = h >> 2;
  int t = threadIdx.x, w = t >> 6, l = t & 63;
  int lane15 = l & 15, quad = l >> 4;

  __shared__ alignas(16) bf16_t Ks[16 * 512];
  __shared__ alignas(16) bf16_t Vs[16 * 512];
  __shared__ alignas(16) bf16_t Ps[4][32 * 68];

  bf16x8 aq[2][4];
#pragma unroll
  for (int i = 0; i < 2; i++)
#pragma unroll
    for (int kk = 0; kk < 4; kk++)
      aq[i][kk] = *(const bf16x8*)(qg +
          (size_t)(qblk * 128 + w * 32 + i * 16 + lane15) * HID +
          h * HD + kk * 32 + quad * 8);

  f32x4 o[2][8] = {};
  float lsum[2][4] = {};
  const float scale = 0.08838834764831845f;
  int rowmax_w = qblk * 128 + w * 32 + 31;
  int nk = 2 * qblk + 2;

  for (int kblk = 0; kblk < nk; kblk++) {
    __syncthreads();
#pragma unroll
    for (int kk = 0; kk < 4; kk++)
      async_copy16(&Ks[(w * 4 + kk) * 512],
                   kvg + (size_t)(kblk * 64 + w * 16 + lane15) * KVD +
                       kvh * HD + kk * 32 + quad * 8);
#pragma unroll
    for (int j = 0; j < 4; j++) {
      int tt = w * 2 + (j >> 1), kt2 = j & 1;
      async_copy16(&Vs[(tt * 2 + kt2) * 512],
                   vT + ((size_t)kvh * HD + tt * 16 + lane15) * L_SEQ +
                       kblk * 64 + kt2 * 32 + quad * 8);
    }
    __syncthreads();

    if (kblk * 64 <= rowmax_w) {
      f32x4 sacc[2][4] = {};
#pragma unroll
      for (int n = 0; n < 4; n++)
#pragma unroll
        for (int kk = 0; kk < 4; kk++) {
          bf16x8 b = *(const bf16x8*)&Ks[(n * 4 + kk) * 512 + l * 8];
          sacc[0][n] = __builtin_amdgcn_mfma_f32_16x16x32_bf16(aq[0][kk], b, sacc[0][n], 0, 0, 0);
          sacc[1][n] = __builtin_amdgcn_mfma_f32_16x16x32_bf16(aq[1][kk], b, sacc[1][n], 0, 0, 0);
        }
      bool maskblk = (kblk >= 2 * qblk);
#pragma unroll
      for (int i = 0; i < 2; i++)
#pragma unroll
        for (int n = 0; n < 4; n++) {
          int col = kblk * 64 + n * 16 + lane15;
#pragma unroll
          for (int r = 0; r < 4; r++) {
            float p = __expf(sacc[i][n][r] * scale);
            if (maskblk && col > (qblk * 128 + w * 32 + i * 16 + quad * 4 + r)) p = 0.f;
            lsum[i][r] += p;
            Ps[w][(i * 16 + quad * 4 + r) * 68 + n * 16 + lane15] = __float2bfloat16(p);
          }
        }
#pragma unroll
      for (int i = 0; i < 2; i++)
#pragma unroll
        for (int kt2 = 0; kt2 < 2; kt2++) {
          bf16x8 ap = *(const bf16x8*)&Ps[w][(i * 16 + lane15) * 68 + kt2 * 32 + quad * 8];
#pragma unroll
          for (int tt = 0; tt < 8; tt++) {
            bf16x8 b = *(const bf16x8*)&Vs[(tt * 2 + kt2) * 512 + l * 8];
            o[i][tt] = __builtin_amdgcn_mfma_f32_16x16x32_bf16(ap, b, o[i][tt], 0, 0, 0);
          }
        }
    }
  }

  float inv[2][4];
#pragma unroll
  for (int i = 0; i < 2; i++)
#pragma unroll
    for (int r = 0; r < 4; r++) {
      float s = lsum[i][r];
#pragma unroll
      for (int off = 1; off < 16; off <<= 1) s += __shfl_xor(s, off, 64);
      inv[i][r] = 1.f / s;
    }
  int qrow0 = qblk * 128 + w * 32;
#pragma unroll
  for (int i = 0; i < 2; i++)
#pragma unroll
    for (int tt = 0; tt < 8; tt++) {
      int col = h * HD + tt * 16 + lane15;
#pragma unroll
      for (int r = 0; r < 4; r++)
        attn[(size_t)(qrow0 + i * 16 + quad * 4 + r) * HID + col] =
            __float2bfloat16(o[i][tt][r] * inv[i][r]);
    }
}

// ---------------- Launch --------------------------------------------------
extern "C" void kernel_launch(void* const* d_in, const int* in_sizes, int n_in,
                              void* d_out, int out_size, void* d_ws, size_t ws_size,
                              hipStream_t stream) {
  const float* x    = (const float*)d_in[0];
  const float* cosT = (const float*)d_in[1];
  const float* sinT = (const float*)d_in[2];
  const float* kc_in = (const float*)d_in[5];
  const float* vc_in = (const float*)d_in[6];
  const float* ln_w  = (const float*)d_in[7];
  const float* Wq = (const float*)d_in[8];
  const float* Wk = (const float*)d_in[9];
  const float* Wv = (const float*)d_in[10];
  const float* Wo = (const float*)d_in[11];

  float* out    = (float*)d_out;
  float* kc_out = out + (size_t)L_SEQ * HID;
  float* vc_out = kc_out + (size_t)MAXP * NKV * HD;

  char* ws = (char*)d_ws;
  bf16_t* h_bf   = (bf16_t*)(ws + 0);              // 16 MB
  bf16_t* Wbuf   = (bf16_t*)(ws + 16777216);       // 32 MB: Wq, later Wo
  bf16_t* Wk_bf  = (bf16_t*)(ws + 50331648);       // 8 MB
  bf16_t* Wv_bf  = (bf16_t*)(ws + 58720256);       // 8 MB (contiguous after Wk)
  bf16_t* attn_bf= (bf16_t*)(ws + 50331648);       // 16 MB (reuses Wk+Wv)
  bf16_t* q_bf   = (bf16_t*)(ws + 67108864);       // 16 MB
  bf16_t* kv_bf  = (bf16_t*)(ws + 83886080);       // 8 MB
  bf16_t* vT_bf  = (bf16_t*)(ws + 92274688);       // 4 MB

  rmsnorm_kernel<<<L_SEQ, 256, 0, stream>>>(x, ln_w, h_bf);
  cvt_bf16_kernel<<<(HID * HID) / (8 * 256), 256, 0, stream>>>(Wq, Wbuf);
  cvt_bf16_kernel<<<(NKV * HD * HID) / (8 * 256), 256, 0, stream>>>(Wk, Wk_bf);
  cvt_bf16_kernel<<<(NKV * HD * HID) / (8 * 256), 256, 0, stream>>>(Wv, Wv_bf);

  gemm_bt_kernel<0><<<dim3(HID / 128, L_SEQ / 128), 256, 0, stream>>>(
      h_bf, Wbuf, q_bf, nullptr, nullptr, HID, HID);
  gemm_bt_kernel<0><<<dim3(KVD / 128, L_SEQ / 128), 256, 0, stream>>>(
      h_bf, Wk_bf, kv_bf, nullptr, nullptr, KVD, HID);

  rope_kernel<<<(L_SEQ * (NH + NKV) * 64) / 256, 256, 0, stream>>>(
      q_bf, kv_bf, cosT, sinT, kc_out);
  vtrans_kernel<<<dim3(NKV, L_SEQ / 64, HD / 64), 256, 0, stream>>>(
      kv_bf, vc_out, vT_bf);
  cache_tail_kernel<<<((MAXP - L_SEQ) * NKV * HD) / (4 * 256), 256, 0, stream>>>(
      kc_in, vc_in, kc_out, vc_out);

  cvt_bf16_kernel<<<(HID * HID) / (8 * 256), 256, 0, stream>>>(Wo, Wbuf);

  attn_kernel<<<dim3(NH, L_SEQ / 128), 256, 0, stream>>>(q_bf, kv_bf, vT_bf, attn_bf);

  gemm_bt_kernel<1><<<dim3(HID / 128, L_SEQ / 128), 256, 0, stream>>>(
      attn_bf, Wbuf, nullptr, out, x, HID, HID);
}

// Round 3
// 687.560 us; speedup vs baseline: 1.1157x; 1.1157x over previous
//
#include <hip/hip_runtime.h>
#include <hip/hip_bf16.h>
#include <cstdint>

#define L_SEQ 2048
#define HID   4096
#define NH    32
#define NKV   8
#define HD    128
#define MAXP  4096
#define QKVD  6144          // fused Q|K|V projection width
#define K_OFF 4096
#define V_OFF 5120

using bf16_t = __hip_bfloat16;
typedef __bf16 bf16x8 __attribute__((ext_vector_type(8)));
typedef float  f32x4  __attribute__((ext_vector_type(4)));
typedef short  short4v __attribute__((ext_vector_type(4)));
typedef short  short8v __attribute__((ext_vector_type(8)));

__device__ __forceinline__ void async_copy16(void* lds, const void* g) {
  __builtin_amdgcn_global_load_lds(
      (__attribute__((address_space(1))) void*)g,
      (__attribute__((address_space(3))) void*)lds, 16, 0, 0);
}

// ---------------- RMSNorm: x (L,HID) f32 -> h (L,HID) bf16 ----------------
__global__ __launch_bounds__(256) void rmsnorm_kernel(
    const float* __restrict__ x, const float* __restrict__ w,
    bf16_t* __restrict__ h) {
  int row = blockIdx.x, t = threadIdx.x;
  const float4* xv = (const float4*)(x + (size_t)row * HID);
  float4 v[4];
  float ss = 0.f;
#pragma unroll
  for (int i = 0; i < 4; i++) {
    v[i] = xv[i * 256 + t];
    ss += v[i].x * v[i].x + v[i].y * v[i].y + v[i].z * v[i].z + v[i].w * v[i].w;
  }
#pragma unroll
  for (int off = 32; off >= 1; off >>= 1) ss += __shfl_xor(ss, off, 64);
  __shared__ float red[4];
  if ((t & 63) == 0) red[t >> 6] = ss;
  __syncthreads();
  float rr = rsqrtf((red[0] + red[1] + red[2] + red[3]) * (1.0f / HID) + 1e-5f);
  const float4* wv = (const float4*)w;
  bf16_t* hr = h + (size_t)row * HID;
#pragma unroll
  for (int i = 0; i < 4; i++) {
    float4 wl = wv[i * 256 + t];
    bf16_t tmp[4];
    tmp[0] = __float2bfloat16(v[i].x * rr * wl.x);
    tmp[1] = __float2bfloat16(v[i].y * rr * wl.y);
    tmp[2] = __float2bfloat16(v[i].z * rr * wl.z);
    tmp[3] = __float2bfloat16(v[i].w * rr * wl.w);
    *(short4v*)(hr + (size_t)(i * 256 + t) * 4) = *(short4v*)tmp;
  }
}

// ---------------- f32 -> bf16 convert ----------------
__global__ __launch_bounds__(256) void cvt_bf16_kernel(
    const float* __restrict__ src, bf16_t* __restrict__ dst) {
  size_t i = ((size_t)blockIdx.x * 256 + threadIdx.x) * 8;
  float4 a = *(const float4*)(src + i);
  float4 b = *(const float4*)(src + i + 4);
  bf16_t tmp[8] = {__float2bfloat16(a.x), __float2bfloat16(a.y),
                   __float2bfloat16(a.z), __float2bfloat16(a.w),
                   __float2bfloat16(b.x), __float2bfloat16(b.y),
                   __float2bfloat16(b.z), __float2bfloat16(b.w)};
  *(short8v*)(dst + i) = *(short8v*)tmp;
}

// ---- GEMM: C(MxN) = A(MxK) @ B(NxK)^T, frag-ordered LDS, double-buffered --
// Single barrier per K-step: barrier drains tile k (issued last iter),
// then prefetch tile k+1 into the other buffer overlaps compute on tile k.
template <int OUT_MODE>
__global__ __launch_bounds__(256) void gemm_bt_kernel(
    const bf16_t* __restrict__ A, const bf16_t* __restrict__ B,
    bf16_t* __restrict__ Cb, float* __restrict__ Cf,
    const float* __restrict__ resid, int N, int K) {
  __shared__ alignas(16) bf16_t As[2][8 * 512];
  __shared__ alignas(16) bf16_t Bs[2][8 * 512];
  int t = threadIdx.x;
  int l = t & 63;
  int lane15 = l & 15, quad = l >> 4;
  int w = t >> 6;
  int wm = w >> 1, wn = w & 1;
  const bf16_t* Ag = A + (size_t)blockIdx.y * 128 * K;
  const bf16_t* Bg = B + (size_t)blockIdx.x * 128 * K;
  int p0 = w * 2, p1 = w * 2 + 1;
  const bf16_t* Ag0 = Ag + (size_t)(p0 * 16 + lane15) * K + quad * 8;
  const bf16_t* Ag1 = Ag + (size_t)(p1 * 16 + lane15) * K + quad * 8;
  const bf16_t* Bg0 = Bg + (size_t)(p0 * 16 + lane15) * K + quad * 8;
  const bf16_t* Bg1 = Bg + (size_t)(p1 * 16 + lane15) * K + quad * 8;

  // prologue: stage tile 0 into buffer 0
  async_copy16(&As[0][p0 * 512], Ag0);
  async_copy16(&As[0][p1 * 512], Ag1);
  async_copy16(&Bs[0][p0 * 512], Bg0);
  async_copy16(&Bs[0][p1 * 512], Bg1);

  f32x4 acc[4][4] = {};
  int nk = K >> 5;
  for (int ki = 0; ki < nk; ki++) {
    __syncthreads();  // vmcnt(0) drain: tile ki has arrived; prior reads done
    if (ki + 1 < nk) {
      int kt = (ki + 1) << 5;
      int nb = (ki + 1) & 1;
      async_copy16(&As[nb][p0 * 512], Ag0 + kt);
      async_copy16(&As[nb][p1 * 512], Ag1 + kt);
      async_copy16(&Bs[nb][p0 * 512], Bg0 + kt);
      async_copy16(&Bs[nb][p1 * 512], Bg1 + kt);
    }
    int b = ki & 1;
    bf16x8 af[4], bfr[4];
#pragma unroll
    for (int i = 0; i < 4; i++)
      af[i] = *(const bf16x8*)&As[b][(wm * 4 + i) * 512 + l * 8];
#pragma unroll
    for (int j = 0; j < 4; j++)
      bfr[j] = *(const bf16x8*)&Bs[b][(wn * 4 + j) * 512 + l * 8];
#pragma unroll
    for (int i = 0; i < 4; i++)
#pragma unroll
      for (int j = 0; j < 4; j++)
        acc[i][j] = __builtin_amdgcn_mfma_f32_16x16x32_bf16(af[i], bfr[j],
                                                            acc[i][j], 0, 0, 0);
  }
  int row0 = blockIdx.y * 128 + wm * 64 + quad * 4;
  int col0 = blockIdx.x * 128 + wn * 64 + lane15;
#pragma unroll
  for (int i = 0; i < 4; i++)
#pragma unroll
    for (int j = 0; j < 4; j++)
#pragma unroll
      for (int r = 0; r < 4; r++) {
        size_t idx = (size_t)(row0 + i * 16 + r) * N + col0 + j * 16;
        if (OUT_MODE == 0)
          Cb[idx] = __float2bfloat16(acc[i][j][r]);
        else
          Cf[idx] = acc[i][j][r] + resid[idx];
      }
}

// ---------------- RoPE in-place on fused qkv (L, QKVD) --------------------
__global__ __launch_bounds__(256) void rope_kernel(
    bf16_t* __restrict__ qkv,
    const float* __restrict__ cosT, const float* __restrict__ sinT,
    float* __restrict__ kc_out) {
  int idx = blockIdx.x * 256 + threadIdx.x;  // L*(NH+NKV)*64
  int d = idx & 63;
  int rest = idx >> 6;
  int hh = rest % (NH + NKV);
  int pos = rest / (NH + NKV);
  float c = cosT[pos * HD + d];
  float s = sinT[pos * HD + d];
  bf16_t* b = (hh < NH)
      ? qkv + (size_t)pos * QKVD + hh * HD
      : qkv + (size_t)pos * QKVD + K_OFF + (hh - NH) * HD;
  float x1 = __bfloat162float(b[d]);
  float x2 = __bfloat162float(b[d + 64]);
  float o1 = x1 * c - x2 * s;
  float o2 = x2 * c + x1 * s;
  b[d] = __float2bfloat16(o1);
  b[d + 64] = __float2bfloat16(o2);
  if (hh >= NH) {
    float* kc = kc_out + (size_t)pos * (NKV * HD) + (hh - NH) * HD;
    kc[d] = o1;
    kc[d + 64] = o2;
  }
}

// ---------------- V transpose via LDS + v_cache fp32 write ----------------
__global__ __launch_bounds__(256) void vtrans_kernel(
    const bf16_t* __restrict__ qkv, float* __restrict__ vc_out,
    bf16_t* __restrict__ vT) {
  __shared__ alignas(16) short Ts[64 * 64];
  int kvh = blockIdx.x, pb = blockIdx.y, db = blockIdx.z;
  int t = threadIdx.x;
  int r = t & 63;
  int c4 = t >> 6;
  const short* src = (const short*)(qkv + (size_t)(pb * 64 + r) * QKVD +
                                    V_OFF + kvh * HD + db * 64 + c4 * 16);
  short8v v0 = *(const short8v*)src;
  short8v v1 = *(const short8v*)(src + 8);
  float* vo = vc_out + (size_t)(pb * 64 + r) * (NKV * HD) + kvh * HD + db * 64 + c4 * 16;
  float tmpf[16];
#pragma unroll
  for (int j = 0; j < 8; j++) {
    tmpf[j]     = __uint_as_float(((unsigned)(unsigned short)v0[j]) << 16);
    tmpf[j + 8] = __uint_as_float(((unsigned)(unsigned short)v1[j]) << 16);
  }
#pragma unroll
  for (int j = 0; j < 4; j++)
    ((float4*)vo)[j] = make_float4(tmpf[j * 4], tmpf[j * 4 + 1],
                                   tmpf[j * 4 + 2], tmpf[j * 4 + 3]);
  int cs = c4 ^ (r & 3);
  *(short8v*)&Ts[r * 64 + cs * 16] = v0;
  *(short8v*)&Ts[r * 64 + cs * 16 + 8] = v1;
  __syncthreads();
  int dr = t & 63;
  int pc = t >> 6;
  short vals[16];
#pragma unroll
  for (int j = 0; j < 16; j++) {
    int pos = pc * 16 + j;
    int cc = (dr >> 4) ^ (pos & 3);
    vals[j] = Ts[pos * 64 + cc * 16 + (dr & 15)];
  }
  short* dst = (short*)(vT + ((size_t)kvh * HD + db * 64 + dr) * L_SEQ + pb * 64 + pc * 16);
  *(short8v*)dst = *(short8v*)&vals[0];
  *(short8v*)(dst + 8) = *(short8v*)&vals[8];
}

// ---------------- cache tail copy (pos >= L) ------------------------------
__global__ __launch_bounds__(256) void cache_tail_kernel(
    const float* __restrict__ kc_in, const float* __restrict__ vc_in,
    float* __restrict__ kc_out, float* __restrict__ vc_out) {
  size_t base = (size_t)L_SEQ * NKV * HD;
  size_t i = base + ((size_t)blockIdx.x * 256 + threadIdx.x) * 4;
  *(float4*)(kc_out + i) = *(const float4*)(kc_in + i);
  *(float4*)(vc_out + i) = *(const float4*)(vc_in + i);
}

// ---------------- Flash attention: block = (head, 128-row Q tile) ---------
__global__ __launch_bounds__(256) void attn_kernel(
    const bf16_t* __restrict__ qkv, const bf16_t* __restrict__ vT,
    bf16_t* __restrict__ attn) {
  int h = blockIdx.x;
  int qblk = blockIdx.y;
  int kvh = h >> 2;
  int t = threadIdx.x, w = t >> 6, l = t & 63;
  int lane15 = l & 15, quad = l >> 4;

  __shared__ alignas(16) bf16_t Ks[16 * 512];
  __shared__ alignas(16) bf16_t Vs[16 * 512];
  __shared__ alignas(16) bf16_t Ps[4][32 * 68];

  bf16x8 aq[2][4];
#pragma unroll
  for (int i = 0; i < 2; i++)
#pragma unroll
    for (int kk = 0; kk < 4; kk++)
      aq[i][kk] = *(const bf16x8*)(qkv +
          (size_t)(qblk * 128 + w * 32 + i * 16 + lane15) * QKVD +
          h * HD + kk * 32 + quad * 8);

  f32x4 o[2][8] = {};
  float lsum[2][4] = {};
  const float scale = 0.08838834764831845f;
  int rowmax_w = qblk * 128 + w * 32 + 31;
  int nk = 2 * qblk + 2;

  for (int kblk = 0; kblk < nk; kblk++) {
    __syncthreads();
#pragma unroll
    for (int kk = 0; kk < 4; kk++)
      async_copy16(&Ks[(w * 4 + kk) * 512],
                   qkv + (size_t)(kblk * 64 + w * 16 + lane15) * QKVD +
                       K_OFF + kvh * HD + kk * 32 + quad * 8);
#pragma unroll
    for (int j = 0; j < 4; j++) {
      int tt = w * 2 + (j >> 1), kt2 = j & 1;
      async_copy16(&Vs[(tt * 2 + kt2) * 512],
                   vT + ((size_t)kvh * HD + tt * 16 + lane15) * L_SEQ +
                       kblk * 64 + kt2 * 32 + quad * 8);
    }
    __syncthreads();

    if (kblk * 64 <= rowmax_w) {
      f32x4 sacc[2][4] = {};
#pragma unroll
      for (int n = 0; n < 4; n++)
#pragma unroll
        for (int kk = 0; kk < 4; kk++) {
          bf16x8 b = *(const bf16x8*)&Ks[(n * 4 + kk) * 512 + l * 8];
          sacc[0][n] = __builtin_amdgcn_mfma_f32_16x16x32_bf16(aq[0][kk], b, sacc[0][n], 0, 0, 0);
          sacc[1][n] = __builtin_amdgcn_mfma_f32_16x16x32_bf16(aq[1][kk], b, sacc[1][n], 0, 0, 0);
        }
      bool maskblk = (kblk >= 2 * qblk);
#pragma unroll
      for (int i = 0; i < 2; i++)
#pragma unroll
        for (int n = 0; n < 4; n++) {
          int col = kblk * 64 + n * 16 + lane15;
#pragma unroll
          for (int r = 0; r < 4; r++) {
            float p = __expf(sacc[i][n][r] * scale);
            if (maskblk && col > (qblk * 128 + w * 32 + i * 16 + quad * 4 + r)) p = 0.f;
            lsum[i][r] += p;
            Ps[w][(i * 16 + quad * 4 + r) * 68 + n * 16 + lane15] = __float2bfloat16(p);
          }
        }
#pragma unroll
      for (int i = 0; i < 2; i++)
#pragma unroll
        for (int kt2 = 0; kt2 < 2; kt2++) {
          bf16x8 ap = *(const bf16x8*)&Ps[w][(i * 16 + lane15) * 68 + kt2 * 32 + quad * 8];
#pragma unroll
          for (int tt = 0; tt < 8; tt++) {
            bf16x8 b = *(const bf16x8*)&Vs[(tt * 2 + kt2) * 512 + l * 8];
            o[i][tt] = __builtin_amdgcn_mfma_f32_16x16x32_bf16(ap, b, o[i][tt], 0, 0, 0);
          }
        }
    }
  }

  float inv[2][4];
#pragma unroll
  for (int i = 0; i < 2; i++)
#pragma unroll
    for (int r = 0; r < 4; r++) {
      float s = lsum[i][r];
#pragma unroll
      for (int off = 1; off < 16; off <<= 1) s += __shfl_xor(s, off, 64);
      inv[i][r] = 1.f / s;
    }
  int qrow0 = qblk * 128 + w * 32;
#pragma unroll
  for (int i = 0; i < 2; i++)
#pragma unroll
    for (int tt = 0; tt < 8; tt++) {
      int col = h * HD + tt * 16 + lane15;
#pragma unroll
      for (int r = 0; r < 4; r++)
        attn[(size_t)(qrow0 + i * 16 + quad * 4 + r) * HID + col] =
            __float2bfloat16(o[i][tt][r] * inv[i][r]);
    }
}

// ---------------- Launch --------------------------------------------------
extern "C" void kernel_launch(void* const* d_in, const int* in_sizes, int n_in,
                              void* d_out, int out_size, void* d_ws, size_t ws_size,
                              hipStream_t stream) {
  const float* x    = (const float*)d_in[0];
  const float* cosT = (const float*)d_in[1];
  const float* sinT = (const float*)d_in[2];
  const float* kc_in = (const float*)d_in[5];
  const float* vc_in = (const float*)d_in[6];
  const float* ln_w  = (const float*)d_in[7];
  const float* Wq = (const float*)d_in[8];
  const float* Wk = (const float*)d_in[9];
  const float* Wv = (const float*)d_in[10];
  const float* Wo = (const float*)d_in[11];

  float* out    = (float*)d_out;
  float* kc_out = out + (size_t)L_SEQ * HID;
  float* vc_out = kc_out + (size_t)MAXP * NKV * HD;

  // Workspace (92 MB total):
  //  [0,16M):   h_bf, later attn_bf (h dead after QKV GEMM)
  //  [16M,64M): Wqkv_bf (48 MB), later Wo_bf (32 MB, after QKV GEMM)
  //  [64M,88M): qkv_bf (L x 6144 bf16, 24 MB)
  //  [88M,92M): vT_bf (NKV,HD,L bf16, 4 MB)
  char* ws = (char*)d_ws;
  bf16_t* h_bf    = (bf16_t*)(ws + 0);
  bf16_t* attn_bf = (bf16_t*)(ws + 0);
  bf16_t* Wqkv_bf = (bf16_t*)(ws + 16777216);
  bf16_t* Wo_bf   = (bf16_t*)(ws + 16777216);
  bf16_t* qkv_bf  = (bf16_t*)(ws + 67108864);
  bf16_t* vT_bf   = (bf16_t*)(ws + 92274688);

  rmsnorm_kernel<<<L_SEQ, 256, 0, stream>>>(x, ln_w, h_bf);
  cvt_bf16_kernel<<<(HID * HID) / (8 * 256), 256, 0, stream>>>(Wq, Wqkv_bf);
  cvt_bf16_kernel<<<(NKV * HD * HID) / (8 * 256), 256, 0, stream>>>(
      Wk, Wqkv_bf + (size_t)K_OFF * HID);
  cvt_bf16_kernel<<<(NKV * HD * HID) / (8 * 256), 256, 0, stream>>>(
      Wv, Wqkv_bf + (size_t)V_OFF * HID);

  // Fused QKV = h @ Wqkv^T  -> qkv_bf (L, 6144); 768 blocks = 3/CU
  gemm_bt_kernel<0><<<dim3(QKVD / 128, L_SEQ / 128), 256, 0, stream>>>(
      h_bf, Wqkv_bf, qkv_bf, nullptr, nullptr, QKVD, HID);

  rope_kernel<<<(L_SEQ * (NH + NKV) * 64) / 256, 256, 0, stream>>>(
      qkv_bf, cosT, sinT, kc_out);
  vtrans_kernel<<<dim3(NKV, L_SEQ / 64, HD / 64), 256, 0, stream>>>(
      qkv_bf, vc_out, vT_bf);
  cache_tail_kernel<<<((MAXP - L_SEQ) * NKV * HD) / (4 * 256), 256, 0, stream>>>(
      kc_in, vc_in, kc_out, vc_out);

  cvt_bf16_kernel<<<(HID * HID) / (8 * 256), 256, 0, stream>>>(Wo, Wo_bf);

  attn_kernel<<<dim3(NH, L_SEQ / 128), 256, 0, stream>>>(qkv_bf, vT_bf, attn_bf);

  gemm_bt_kernel<1><<<dim3(HID / 128, L_SEQ / 128), 256, 0, stream>>>(
      attn_bf, Wo_bf, nullptr, out, x, HID, HID);
}